// Round 10
// baseline (288.915 us; speedup 1.0000x reference)
//
#include <hip/hip_runtime.h>

// CellList — all i<j pairs of N atoms, cutoff 5.2. Output: FLOAT32, flat,
// 7P elements, P = N(N-1)/2:
//   [0,P) i | [P,2P) j | [2P,3P) in_cutoff | [3P,6P) diff*mask | [6P,7P) dist
//
// Store-BW bound (528 MB mandatory). Forensics:
//  r6: nontemporal -> L2 merge defeated (988 MB written, 2.4 TB/s).
//  r7: 8 pairs/thread -> VGPR 124 -> 155 us.
//  r8: LDS-densified diff ~neutral (L2 merges interleaved wave stores).
//  r9: persistent blocks ~neutral (dispatch not limiting). Flat 5.2 TB/s.
// r10 experiment: PHASE SPLIT — 5 kernels, each writing ONE contiguous
// stream (fill-like locality), testing the concurrent-stream/row-thrash
// hypothesis for the 5.2 vs 6.9 TB/s gap.

static __device__ __forceinline__ void decode_ij(int p0, int N, int twoNm1,
                                                 int& io, int& jo) {
    // rows(i) = i*(2N-1-i)/2; exact int64 disc, f32 sqrt, int correction.
    long long disc_i = (long long)twoNm1 * (long long)twoNm1 - 8LL * (long long)p0;
    float sr = __fsqrt_rn((float)disc_i);
    int i = (int)(((float)twoNm1 - sr) * 0.5f);
    if (i < 0) i = 0;
    if (i > N - 2) i = N - 2;
    long long ri = ((long long)i * (long long)(twoNm1 - i)) >> 1;
    while (i < N - 2) {
        long long rn = ((long long)(i + 1) * (long long)(twoNm1 - (i + 1))) >> 1;
        if (rn <= (long long)p0) { ++i; ri = rn; } else break;
    }
    while (i > 0 && ri > (long long)p0) {
        --i; ri = ((long long)i * (long long)(twoNm1 - i)) >> 1;
    }
    io = i;
    jo = i + 1 + (int)((long long)p0 - ri);
}

// pair geometry, numpy-exact f32: (dx*dx + dy*dy) + dz*dz, no FMA contraction
static __device__ __forceinline__ float pair_mask_d(
    const int* species, const float* coords, int i, int j,
    float& dx, float& dy, float& dz, float& d) {
    dx = coords[3 * i + 0] - coords[3 * j + 0];
    dy = coords[3 * i + 1] - coords[3 * j + 1];
    dz = coords[3 * i + 2] - coords[3 * j + 2];
    float sq = __fadd_rn(__fadd_rn(__fmul_rn(dx, dx), __fmul_rn(dy, dy)),
                         __fmul_rn(dz, dz));
    d = __fsqrt_rn(sq);
    bool inc = (d <= 5.2f) && (species[i] != -1) && (species[j] != -1);
    return inc ? 1.0f : 0.0f;
}

// ---- K_index: write i (WHICH=0) or j (WHICH=1). 16 pairs/thread. ----
template <int WHICH>
__global__ __launch_bounds__(256) void k_index(float* __restrict__ dst,
                                               int N, int P) {
    int g  = blockIdx.x * blockDim.x + threadIdx.x;
    int p0 = g << 4;
    if (p0 >= P) return;
    const int twoNm1 = 2 * N - 1;
    int i, j; decode_ij(p0, N, twoNm1, i, j);
    int nk = P - p0; if (nk > 16) nk = 16;
    if (nk == 16) {
        float v[16];
#pragma unroll 16
        for (int k = 0; k < 16; ++k) {
            if (j >= N) { ++i; j = i + 1; }
            v[k] = WHICH ? (float)j : (float)i;
            ++j;
        }
        float4* o = reinterpret_cast<float4*>(dst + (size_t)p0);
        o[0] = make_float4(v[0],  v[1],  v[2],  v[3]);
        o[1] = make_float4(v[4],  v[5],  v[6],  v[7]);
        o[2] = make_float4(v[8],  v[9],  v[10], v[11]);
        o[3] = make_float4(v[12], v[13], v[14], v[15]);
    } else {
        for (int k = 0; k < nk; ++k) {
            if (j >= N) { ++i; j = i + 1; }
            dst[(size_t)p0 + k] = WHICH ? (float)j : (float)i;
            ++j;
        }
    }
}

// ---- K_scalar: write cutoff mask (MODE=0) or dist (MODE=1). 16 pairs/thread. ----
template <int MODE>
__global__ __launch_bounds__(256) void k_scalar(
    const int* __restrict__ species, const float* __restrict__ coords,
    float* __restrict__ dst, int N, int P) {
    int g  = blockIdx.x * blockDim.x + threadIdx.x;
    int p0 = g << 4;
    if (p0 >= P) return;
    const int twoNm1 = 2 * N - 1;
    int i, j; decode_ij(p0, N, twoNm1, i, j);
    int nk = P - p0; if (nk > 16) nk = 16;
    if (nk == 16) {
        float v[16];
#pragma unroll 16
        for (int k = 0; k < 16; ++k) {
            if (j >= N) { ++i; j = i + 1; }
            float dx, dy, dz, d;
            float m = pair_mask_d(species, coords, i, j, dx, dy, dz, d);
            v[k] = MODE ? __fmul_rn(d, m) : m;
            ++j;
        }
        float4* o = reinterpret_cast<float4*>(dst + (size_t)p0);
        o[0] = make_float4(v[0],  v[1],  v[2],  v[3]);
        o[1] = make_float4(v[4],  v[5],  v[6],  v[7]);
        o[2] = make_float4(v[8],  v[9],  v[10], v[11]);
        o[3] = make_float4(v[12], v[13], v[14], v[15]);
    } else {
        for (int k = 0; k < nk; ++k) {
            if (j >= N) { ++i; j = i + 1; }
            float dx, dy, dz, d;
            float m = pair_mask_d(species, coords, i, j, dx, dy, dz, d);
            dst[(size_t)p0 + k] = MODE ? __fmul_rn(d, m) : m;
            ++j;
        }
    }
}

// ---- K_diff: write diff [P,3] as one contiguous 3P stream. 8 pairs/thread. ----
__global__ __launch_bounds__(256) void k_diff(
    const int* __restrict__ species, const float* __restrict__ coords,
    float* __restrict__ dst, int N, int P) {
    int g  = blockIdx.x * blockDim.x + threadIdx.x;
    int p0 = g << 3;
    if (p0 >= P) return;
    const int twoNm1 = 2 * N - 1;
    int i, j; decode_ij(p0, N, twoNm1, i, j);
    int nk = P - p0; if (nk > 8) nk = 8;
    if (nk == 8) {
        float v[24];
#pragma unroll 8
        for (int k = 0; k < 8; ++k) {
            if (j >= N) { ++i; j = i + 1; }
            float dx, dy, dz, d;
            float m = pair_mask_d(species, coords, i, j, dx, dy, dz, d);
            v[3 * k + 0] = __fmul_rn(dx, m);
            v[3 * k + 1] = __fmul_rn(dy, m);
            v[3 * k + 2] = __fmul_rn(dz, m);
            ++j;
        }
        float4* o = reinterpret_cast<float4*>(dst + 3 * (size_t)p0);
        o[0] = make_float4(v[0],  v[1],  v[2],  v[3]);
        o[1] = make_float4(v[4],  v[5],  v[6],  v[7]);
        o[2] = make_float4(v[8],  v[9],  v[10], v[11]);
        o[3] = make_float4(v[12], v[13], v[14], v[15]);
        o[4] = make_float4(v[16], v[17], v[18], v[19]);
        o[5] = make_float4(v[20], v[21], v[22], v[23]);
    } else {
        for (int k = 0; k < nk; ++k) {
            if (j >= N) { ++i; j = i + 1; }
            float dx, dy, dz, d;
            float m = pair_mask_d(species, coords, i, j, dx, dy, dz, d);
            dst[3 * ((size_t)p0 + k) + 0] = __fmul_rn(dx, m);
            dst[3 * ((size_t)p0 + k) + 1] = __fmul_rn(dy, m);
            dst[3 * ((size_t)p0 + k) + 2] = __fmul_rn(dz, m);
            ++j;
        }
    }
}

extern "C" void kernel_launch(void* const* d_in, const int* in_sizes, int n_in,
                              void* d_out, int out_size, void* d_ws, size_t ws_size,
                              hipStream_t stream) {
    const int*   species = (const int*)d_in[0];
    const float* coords  = (const float*)d_in[1];
    float*       out     = (float*)d_out;
    int N = in_sizes[0];
    long long Pll = (long long)N * (long long)(N - 1) / 2;
    int P = (int)Pll;
    size_t Ps = (size_t)P;

    long long g16 = (Pll + 15) >> 4;                 // threads for 16-pair kernels
    long long b16 = (g16 + 255) / 256;
    long long g8  = (Pll + 7) >> 3;                  // threads for 8-pair kernel
    long long b8  = (g8 + 255) / 256;

    k_index<0><<<dim3((unsigned)b16), dim3(256), 0, stream>>>(out, N, P);
    k_index<1><<<dim3((unsigned)b16), dim3(256), 0, stream>>>(out + Ps, N, P);
    k_scalar<0><<<dim3((unsigned)b16), dim3(256), 0, stream>>>(species, coords,
                                                               out + 2 * Ps, N, P);
    k_diff<<<dim3((unsigned)b8), dim3(256), 0, stream>>>(species, coords,
                                                         out + 3 * Ps, N, P);
    k_scalar<1><<<dim3((unsigned)b16), dim3(256), 0, stream>>>(species, coords,
                                                               out + 6 * Ps, N, P);
}

// Round 11
// 102.409 us; speedup vs baseline: 2.8212x; 2.8212x over previous
//
#include <hip/hip_runtime.h>

// CellList — all i<j pairs of N atoms, cutoff 5.2. Output: FLOAT32, flat,
// 7P elements, P = N(N-1)/2:
//   [0,P) i | [P,2P) j | [2P,3P) in_cutoff | [3P,6P) diff*mask | [6P,7P) dist
//
// Store-BW bound (528 MB mandatory). Forensics:
//  r6:  nontemporal -> defeats L2 write-merge (988 MB, 2.4 TB/s). Never nt.
//  r7:  8 pairs/thread -> VGPR 124 -> occupancy drop -> 155 us.
//  r8:  LDS-densified diff ~neutral -> store density is NOT the limiter.
//  r9:  persistent blocks ~neutral -> dispatch is NOT the limiter.
//  r10: phase-split @16 pairs/thread -> 289 us: per-lane j stride 16 makes
//       every coord load a 64-line gather. LOADS are the prime suspect.
// r11: lane-consecutive pair mapping. Wave's 64 lanes = 64 consecutive
// pairs: cj loads stride-12B (12 lines/inst), species dense, ci broadcast.
// Narrow streams: dense dword stores. Diff: LDS transpose (stride-3 words,
// conflict-free) + dense float4 writeback.

__global__ __launch_bounds__(256) void cell_pairs_f32(
    const int* __restrict__ species,
    const float* __restrict__ coords,
    float* __restrict__ out,
    int N, int P)
{
    __shared__ float ldsd[3072];            // 1024 pairs x 3 floats = 12 KB

    const int t   = threadIdx.x;
    const int blk = blockIdx.x << 10;       // 1024 pairs per block
    if (blk >= P) return;
    const bool full = (blk + 1024 <= P);
    const int twoNm1 = 2 * N - 1;
    const size_t Ps = (size_t)P;

    if (full) {
#pragma unroll
        for (int k = 0; k < 4; ++k) {
            const int p = blk + (k << 8) + t;   // lane-consecutive pairs

            // ---- decode (i,j): exact int64 disc, f32 sqrt, int correction ----
            long long disc_i = (long long)twoNm1 * (long long)twoNm1
                             - 8LL * (long long)p;
            float sr = __fsqrt_rn((float)disc_i);
            int i = (int)(((float)twoNm1 - sr) * 0.5f);
            if (i < 0) i = 0;
            if (i > N - 2) i = N - 2;
            long long ri = ((long long)i * (long long)(twoNm1 - i)) >> 1;
            while (i < N - 2) {
                long long rn = ((long long)(i + 1) * (long long)(twoNm1 - (i + 1))) >> 1;
                if (rn <= (long long)p) { ++i; ri = rn; } else break;
            }
            while (i > 0 && ri > (long long)p) {
                --i; ri = ((long long)i * (long long)(twoNm1 - i)) >> 1;
            }
            const int j = i + 1 + (int)((long long)p - ri);

            // ---- pair math (numpy-exact f32, no FMA contraction) ----
            // i is wave-uniform (broadcast); j is lane-consecutive (coalesced)
            float dx = coords[3 * i + 0] - coords[3 * j + 0];
            float dy = coords[3 * i + 1] - coords[3 * j + 1];
            float dz = coords[3 * i + 2] - coords[3 * j + 2];
            float sq = __fadd_rn(__fadd_rn(__fmul_rn(dx, dx), __fmul_rn(dy, dy)),
                                 __fmul_rn(dz, dz));
            float d  = __fsqrt_rn(sq);
            bool inc = (d <= 5.2f) && (species[i] != -1) && (species[j] != -1);
            float m  = inc ? 1.0f : 0.0f;

            // narrow streams: dword stores, 4B/lane dense
            out[(size_t)p]          = (float)i;
            out[Ps + (size_t)p]     = (float)j;
            out[2 * Ps + (size_t)p] = m;
            out[6 * Ps + (size_t)p] = __fmul_rn(d, m);

            // diff -> LDS in flat tile order (stride-3 words: conflict-free)
            const int q = (k << 8) + t;
            ldsd[3 * q + 0] = __fmul_rn(dx, m);
            ldsd[3 * q + 1] = __fmul_rn(dy, m);
            ldsd[3 * q + 2] = __fmul_rn(dz, m);
        }

        __syncthreads();

        // diff writeback: 3 dense chunks of 1024 floats (float4/lane)
        const float4* lr = reinterpret_cast<const float4*>(ldsd);
        float4 d0 = lr[t];
        float4 d1 = lr[t + 256];
        float4 d2 = lr[t + 512];
        float* gd = out + 3 * Ps + 3 * (size_t)blk;
        reinterpret_cast<float4*>(gd)[t]        = d0;
        reinterpret_cast<float4*>(gd + 1024)[t] = d1;
        reinterpret_cast<float4*>(gd + 2048)[t] = d2;
    } else {
        // partial tail block (not hit when P % 1024 == 0): scalar path
        for (int k = 0; k < 4; ++k) {
            const int p = blk + (k << 8) + t;
            if (p >= P) continue;
            long long disc_i = (long long)twoNm1 * (long long)twoNm1
                             - 8LL * (long long)p;
            float sr = __fsqrt_rn((float)disc_i);
            int i = (int)(((float)twoNm1 - sr) * 0.5f);
            if (i < 0) i = 0;
            if (i > N - 2) i = N - 2;
            long long ri = ((long long)i * (long long)(twoNm1 - i)) >> 1;
            while (i < N - 2) {
                long long rn = ((long long)(i + 1) * (long long)(twoNm1 - (i + 1))) >> 1;
                if (rn <= (long long)p) { ++i; ri = rn; } else break;
            }
            while (i > 0 && ri > (long long)p) {
                --i; ri = ((long long)i * (long long)(twoNm1 - i)) >> 1;
            }
            const int j = i + 1 + (int)((long long)p - ri);

            float dx = coords[3 * i + 0] - coords[3 * j + 0];
            float dy = coords[3 * i + 1] - coords[3 * j + 1];
            float dz = coords[3 * i + 2] - coords[3 * j + 2];
            float sq = __fadd_rn(__fadd_rn(__fmul_rn(dx, dx), __fmul_rn(dy, dy)),
                                 __fmul_rn(dz, dz));
            float d  = __fsqrt_rn(sq);
            bool inc = (d <= 5.2f) && (species[i] != -1) && (species[j] != -1);
            float m  = inc ? 1.0f : 0.0f;

            size_t pp = (size_t)p;
            out[pp]                  = (float)i;
            out[Ps + pp]             = (float)j;
            out[2 * Ps + pp]         = m;
            out[3 * Ps + 3 * pp + 0] = __fmul_rn(dx, m);
            out[3 * Ps + 3 * pp + 1] = __fmul_rn(dy, m);
            out[3 * Ps + 3 * pp + 2] = __fmul_rn(dz, m);
            out[6 * Ps + pp]         = __fmul_rn(d, m);
        }
    }
}

extern "C" void kernel_launch(void* const* d_in, const int* in_sizes, int n_in,
                              void* d_out, int out_size, void* d_ws, size_t ws_size,
                              hipStream_t stream) {
    const int*   species = (const int*)d_in[0];
    const float* coords  = (const float*)d_in[1];
    int N = in_sizes[0];
    long long Pll = (long long)N * (long long)(N - 1) / 2;
    int P = (int)Pll;

    long long blocks = (Pll + 1023) >> 10;   // 1024 pairs per block
    cell_pairs_f32<<<dim3((unsigned)blocks), dim3(256), 0, stream>>>(
        species, coords, (float*)d_out, N, P);
}